// Round 8
// baseline (272.426 us; speedup 1.0000x reference)
//
#include <hip/hip_runtime.h>
#include <hip/hip_bf16.h>

// Problem constants (B,S,E,H,D) = (4,2048,1024,16,64)
#define PB 4
#define PS 2048
#define PE 1024
#define PH 16
#define PD 64

typedef __attribute__((ext_vector_type(8))) short bf16x8;
typedef __attribute__((ext_vector_type(4))) float f32x4;
typedef const __attribute__((address_space(1))) unsigned int* gas_t;
typedef __attribute__((address_space(3))) unsigned int* las_t;

__device__ __forceinline__ unsigned short f2bf(float f) {
  union { float f; unsigned int u; } v;
  v.f = f;
  unsigned int u = v.u;
  u += 0x7fffu + ((u >> 16) & 1u);  // RNE
  return (unsigned short)(u >> 16);
}

__device__ __forceinline__ f32x4 mfma16(bf16x8 a, bf16x8 b, f32x4 c) {
  return __builtin_amdgcn_mfma_f32_16x16x32_bf16(a, b, c, 0, 0, 0);
}

// ---------------- fp32 -> bf16 conversion (x, Wk, Wq, Wo fused) --------------
#define CVT_GROUPS ((PB * PS * PE + 3 * PE * PE) / 4)
#define CVT_BLOCKS (CVT_GROUPS / 256)   // 11264
__global__ __launch_bounds__(256) void cvt_kernel(
    const float* __restrict__ x, const float* __restrict__ wk,
    const float* __restrict__ wq, const float* __restrict__ wo,
    unsigned short* __restrict__ xb, unsigned short* __restrict__ wkb,
    unsigned short* __restrict__ wqb, unsigned short* __restrict__ wob) {
  const long long NX = (long long)PB * PS * PE;   // 8388608
  const long long NW = (long long)PE * PE;        // 1048576
  long long i = ((long long)blockIdx.x * 256 + threadIdx.x) * 4;
  const float* src;
  unsigned short* dst;
  long long off;
  if (i < NX)               { src = x;  dst = xb;  off = i; }
  else if (i < NX + NW)     { src = wk; dst = wkb; off = i - NX; }
  else if (i < NX + 2 * NW) { src = wq; dst = wqb; off = i - NX - NW; }
  else                      { src = wo; dst = wob; off = i - NX - 2 * NW; }
  float4 v = *(const float4*)(src + off);
  ushort4 o;
  o.x = f2bf(v.x); o.y = f2bf(v.y); o.z = f2bf(v.z); o.w = f2bf(v.w);
  *(ushort4*)(dst + off) = o;
}

// ---------------- fused Q+K NT GEMM, DOUBLE-BUFFERED ------------------------
// {Q,K}[M,N] = x * {Wq,Wk}^T. 128x128 tile, BK=32. K-loop: stage(0);
// { barrier; stage(k+1 -> other buf); compute(k); } -- the vmcnt(0) drain at
// the barrier now waits on a DMA that flew during the previous compute phase
// (round-7 analysis: old structure serialized ~2000cyc DMA latency per iter).
// LDS slot s of row r holds global chunk s^((r>>1)&3): DMA dest stays
// lane-contiguous; fragment ds_read_b128 -> 2-way bank aliasing (free).
__global__ __launch_bounds__(256) void gemm_qk(
    const unsigned short* __restrict__ A, const unsigned short* __restrict__ Bq,
    const unsigned short* __restrict__ Bk,
    unsigned short* __restrict__ QT, unsigned short* __restrict__ Kb) {
  const int K = PE, N = PE;
  __shared__ __attribute__((aligned(16))) unsigned short As[2][128 * 32];
  __shared__ __attribute__((aligned(16))) unsigned short Bqs[2][128 * 32];
  __shared__ __attribute__((aligned(16))) unsigned short Bks[2][128 * 32];
  const int tid = threadIdx.x;
  const int wave = tid >> 6, lane = tid & 63;
  const int quad = lane >> 4, ln = lane & 15;
  const int m0 = blockIdx.y * 128, n0 = blockIdx.x * 128;
  const int wm = (wave >> 1) * 64, wn = (wave & 1) * 64;

  f32x4 aq[4][4], ak[4][4];
#pragma unroll
  for (int i = 0; i < 4; ++i)
#pragma unroll
    for (int j = 0; j < 4; ++j)
#pragma unroll
      for (int r = 0; r < 4; ++r) { aq[i][j][r] = 0.f; ak[i][j][r] = 0.f; }

  auto stage = [&](int k0, int bufi) {
#pragma unroll
    for (int it = 0; it < 2; ++it) {
      const int idx = it * 256 + tid;
      const int row = it * 64 + (tid >> 2), ch = tid & 3;
      const int gch = ch ^ ((row >> 1) & 3);
      __builtin_amdgcn_global_load_lds(
          (gas_t)(const void*)(A + (size_t)(m0 + row) * K + k0 + gch * 8),
          (las_t)(void*)((char*)As[bufi] + idx * 16), 16, 0, 0);
      __builtin_amdgcn_global_load_lds(
          (gas_t)(const void*)(Bq + (size_t)(n0 + row) * K + k0 + gch * 8),
          (las_t)(void*)((char*)Bqs[bufi] + idx * 16), 16, 0, 0);
      __builtin_amdgcn_global_load_lds(
          (gas_t)(const void*)(Bk + (size_t)(n0 + row) * K + k0 + gch * 8),
          (las_t)(void*)((char*)Bks[bufi] + idx * 16), 16, 0, 0);
    }
  };

  stage(0, 0);
  for (int k0 = 0, kit = 0; k0 < K; k0 += 32, ++kit) {
    __syncthreads();
    if (k0 + 32 < K) stage(k0 + 32, (kit + 1) & 1);
    const unsigned short* as  = As[kit & 1];
    const unsigned short* bqs = Bqs[kit & 1];
    const unsigned short* bks = Bks[kit & 1];
    bf16x8 af[4], bqf[4], bkf[4];
#pragma unroll
    for (int t = 0; t < 4; ++t) {
      const int ra = wm + t * 16 + ln;
      const int rb = wn + t * 16 + ln;
      const int sa = quad ^ ((ra >> 1) & 3);
      const int sb = quad ^ ((rb >> 1) & 3);
      af[t]  = *(const bf16x8*)(as  + ra * 32 + sa * 8);
      bqf[t] = *(const bf16x8*)(bqs + rb * 32 + sb * 8);
      bkf[t] = *(const bf16x8*)(bks + rb * 32 + sb * 8);
    }
#pragma unroll
    for (int mt = 0; mt < 4; ++mt)
#pragma unroll
      for (int nt = 0; nt < 4; ++nt) {
        aq[mt][nt] = mfma16(af[mt], bqf[nt], aq[mt][nt]);
        ak[mt][nt] = mfma16(af[mt], bkf[nt], ak[mt][nt]);
      }
  }

#pragma unroll
  for (int mt = 0; mt < 4; ++mt) {
#pragma unroll
    for (int nt = 0; nt < 4; ++nt) {
      const int row = m0 + wm + mt * 16 + quad * 4;  // +r
      const int col = n0 + wn + nt * 16 + ln;
      // Q: transposed per-head store (4 consecutive tokens -> one 8B store)
      const int b = row >> 11, s = row & 2047;
      const int h = col >> 6, d = col & 63;
      ushort4 ov;
      ov.x = f2bf(aq[mt][nt][0]); ov.y = f2bf(aq[mt][nt][1]);
      ov.z = f2bf(aq[mt][nt][2]); ov.w = f2bf(aq[mt][nt][3]);
      *(ushort4*)(QT + (((size_t)(b * PH + h) * PD + d) * PS + s)) = ov;
      // K: row-major
#pragma unroll
      for (int r = 0; r < 4; ++r)
        Kb[(size_t)(row + r) * N + col] = f2bf(ak[mt][nt][r]);
    }
  }
}

// ---------------- out-projection NT GEMM, DOUBLE-BUFFERED -------------------
__global__ __launch_bounds__(256) void gemm_out(
    const unsigned short* __restrict__ A, const unsigned short* __restrict__ Bm,
    const float* __restrict__ bias, float* __restrict__ Cf) {
  const int K = PE, N = PE;
  __shared__ __attribute__((aligned(16))) unsigned short As[2][128 * 32];
  __shared__ __attribute__((aligned(16))) unsigned short Bs[2][128 * 32];
  const int tid = threadIdx.x;
  const int wave = tid >> 6, lane = tid & 63;
  const int quad = lane >> 4, ln = lane & 15;
  const int m0 = blockIdx.y * 128, n0 = blockIdx.x * 128;
  const int wm = (wave >> 1) * 64, wn = (wave & 1) * 64;

  f32x4 acc[4][4];
#pragma unroll
  for (int i = 0; i < 4; ++i)
#pragma unroll
    for (int j = 0; j < 4; ++j)
#pragma unroll
      for (int r = 0; r < 4; ++r) acc[i][j][r] = 0.f;

  auto stage = [&](int k0, int bufi) {
#pragma unroll
    for (int it = 0; it < 2; ++it) {
      const int idx = it * 256 + tid;
      const int row = it * 64 + (tid >> 2), ch = tid & 3;
      const int gch = ch ^ ((row >> 1) & 3);
      __builtin_amdgcn_global_load_lds(
          (gas_t)(const void*)(A + (size_t)(m0 + row) * K + k0 + gch * 8),
          (las_t)(void*)((char*)As[bufi] + idx * 16), 16, 0, 0);
      __builtin_amdgcn_global_load_lds(
          (gas_t)(const void*)(Bm + (size_t)(n0 + row) * K + k0 + gch * 8),
          (las_t)(void*)((char*)Bs[bufi] + idx * 16), 16, 0, 0);
    }
  };

  stage(0, 0);
  for (int k0 = 0, kit = 0; k0 < K; k0 += 32, ++kit) {
    __syncthreads();
    if (k0 + 32 < K) stage(k0 + 32, (kit + 1) & 1);
    const unsigned short* as = As[kit & 1];
    const unsigned short* bs = Bs[kit & 1];
    bf16x8 af[4], bfr[4];
#pragma unroll
    for (int t = 0; t < 4; ++t) {
      const int ra = wm + t * 16 + ln;
      const int rb = wn + t * 16 + ln;
      af[t]  = *(const bf16x8*)(as + ra * 32 + (quad ^ ((ra >> 1) & 3)) * 8);
      bfr[t] = *(const bf16x8*)(bs + rb * 32 + (quad ^ ((rb >> 1) & 3)) * 8);
    }
#pragma unroll
    for (int mt = 0; mt < 4; ++mt)
#pragma unroll
      for (int nt = 0; nt < 4; ++nt)
        acc[mt][nt] = mfma16(af[mt], bfr[nt], acc[mt][nt]);
  }

#pragma unroll
  for (int mt = 0; mt < 4; ++mt) {
#pragma unroll
    for (int nt = 0; nt < 4; ++nt) {
      const int row = m0 + wm + mt * 16 + quad * 4;
      const int col = n0 + wn + nt * 16 + ln;
      const float bv = bias[col];
#pragma unroll
      for (int r = 0; r < 4; ++r)
        Cf[(size_t)(row + r) * N + col] = acc[mt][nt][r] + bv;
    }
  }
}

// ---------------- fused causal attention, V == Q (reference bug) -------------
// Round-6 structure + DOUBLE-BUFFERED K/V staging (one barrier per iter,
// prefetch of kt+1 flies during compute of kt). ktend is even, so the
// buffer parity across the two passes needs no extra barrier.
__global__ __launch_bounds__(256) void attn_kernel(
    const unsigned short* __restrict__ QT,  // [b,h][d=64][s=2048]
    const unsigned short* __restrict__ Kb,  // [b*s][E] row-major
    unsigned short* __restrict__ Ab) {      // [b*s][E] row-major
  __shared__ __attribute__((aligned(16))) unsigned short Ks[2][64 * 64];
  __shared__ __attribute__((aligned(16))) unsigned short Vs[2][64 * 64];
  __shared__ __attribute__((aligned(16))) unsigned short Ps[4][32 * 72];

  const int tid = threadIdx.x;
  const int wave = tid >> 6, lane = tid & 63;
  const int quad = lane >> 4, ln = lane & 15;
  const int h = blockIdx.y, b = blockIdx.z;
  const size_t hoff  = ((size_t)b * PS) * PE + (size_t)h * PD;
  const size_t hofft = ((size_t)(b * PH + h) * PD) * PS;
  const float CEXP = 0.045084220f;  // log2(e)/32
  const int srow = tid >> 3, sch = tid & 7;

  auto stage = [&](int k0, int bufi) {
#pragma unroll
    for (int r = 0; r < 2; ++r) {
      const int row = r * 32 + srow;
      const int gch = sch ^ (row & 7);
      __builtin_amdgcn_global_load_lds(
          (gas_t)(const void*)(Kb + hoff + (size_t)(k0 + row) * PE + gch * 8),
          (las_t)(void*)((char*)Ks[bufi] + (r * 256 + tid) * 16), 16, 0, 0);
      __builtin_amdgcn_global_load_lds(
          (gas_t)(const void*)(QT + hofft + (size_t)row * PS + k0 + gch * 8),
          (las_t)(void*)((char*)Vs[bufi] + (r * 256 + tid) * 16), 16, 0, 0);
    }
  };

  for (int pass = 0; pass < 2; ++pass) {
    const int qt = pass ? (int)blockIdx.x : 15 - (int)blockIdx.x;
    const int qw0 = qt * 128 + wave * 32;

    bf16x8 qfr[2][2];
#pragma unroll
    for (int nq = 0; nq < 2; ++nq)
#pragma unroll
      for (int c = 0; c < 2; ++c) {
        union { unsigned short u[8]; bf16x8 v; } tmp;
#pragma unroll
        for (int j = 0; j < 8; ++j)
          tmp.u[j] = QT[hofft + (size_t)(c * 32 + quad * 8 + j) * PS +
                        qw0 + nq * 16 + ln];
        qfr[nq][c] = tmp.v;
      }

    f32x4 o[2][4];
    float psum[2];
#pragma unroll
    for (int mq = 0; mq < 2; ++mq)
#pragma unroll
      for (int td = 0; td < 4; ++td)
#pragma unroll
        for (int r = 0; r < 4; ++r) o[mq][td][r] = 0.f;
    psum[0] = psum[1] = 0.f;

    const int ktend = 2 * qt + 2;  // even -> buffer parity safe across passes
    stage(0, 0);
    for (int kt = 0; kt < ktend; ++kt) {
      __syncthreads();
      if (kt + 1 < ktend) stage((kt + 1) * 64, (kt + 1) & 1);
      const int k0 = kt * 64;
      const unsigned short* ks = Ks[kt & 1];
      const unsigned short* vs = Vs[kt & 1];

      f32x4 sacc[4][2];
#pragma unroll
      for (int mk = 0; mk < 4; ++mk)
#pragma unroll
        for (int nq = 0; nq < 2; ++nq)
#pragma unroll
          for (int r = 0; r < 4; ++r) sacc[mk][nq][r] = 0.f;
#pragma unroll
      for (int c = 0; c < 2; ++c) {
        const int ch = ((c * 4 + quad) ^ (ln & 7)) * 8;
        bf16x8 kf[4];
#pragma unroll
        for (int mk = 0; mk < 4; ++mk)
          kf[mk] = *(const bf16x8*)(ks + (mk * 16 + ln) * 64 + ch);
#pragma unroll
        for (int mk = 0; mk < 4; ++mk)
#pragma unroll
          for (int nq = 0; nq < 2; ++nq)
            sacc[mk][nq] = mfma16(kf[mk], qfr[nq][c], sacc[mk][nq]);
      }

      const bool edge = (k0 + 63) > qw0;
#pragma unroll
      for (int mk = 0; mk < 4; ++mk)
#pragma unroll
        for (int nq = 0; nq < 2; ++nq) {
          float p[4];
#pragma unroll
          for (int r = 0; r < 4; ++r)
            p[r] = __builtin_amdgcn_exp2f(sacc[mk][nq][r] * CEXP);
          if (edge) {
            const int qg = qw0 + nq * 16 + ln;
#pragma unroll
            for (int r = 0; r < 4; ++r) {
              const int kg = k0 + mk * 16 + quad * 4 + r;
              p[r] = (kg <= qg) ? p[r] : 0.f;
            }
          }
          psum[nq] += (p[0] + p[1]) + (p[2] + p[3]);
          union { __hip_bfloat162 h2; unsigned int u; } u01, u23;
          u01.h2 = __float22bfloat162_rn(float2{p[0], p[1]});
          u23.h2 = __float22bfloat162_rn(float2{p[2], p[3]});
          *(uint2*)(&Ps[wave][(nq * 16 + ln) * 72 + mk * 16 + quad * 4]) =
              uint2{u01.u, u23.u};
        }

#pragma unroll
      for (int c = 0; c < 2; ++c) {
        const int ch = ((c * 4 + quad) ^ (ln & 7)) * 8;
        bf16x8 pf0 = *(const bf16x8*)(&Ps[wave][ln * 72 + c * 32 + quad * 8]);
        bf16x8 pf1 = *(const bf16x8*)(&Ps[wave][(16 + ln) * 72 + c * 32 + quad * 8]);
#pragma unroll
        for (int td = 0; td < 4; ++td) {
          bf16x8 vfd = *(const bf16x8*)(vs + (td * 16 + ln) * 64 + ch);
          o[0][td] = mfma16(pf0, vfd, o[0][td]);
          o[1][td] = mfma16(pf1, vfd, o[1][td]);
        }
      }
    }

#pragma unroll
    for (int nq = 0; nq < 2; ++nq) {
      psum[nq] += __shfl_xor(psum[nq], 16, 64);
      psum[nq] += __shfl_xor(psum[nq], 32, 64);
    }
    float invq[2][4];
#pragma unroll
    for (int mq = 0; mq < 2; ++mq)
#pragma unroll
      for (int r = 0; r < 4; ++r)
        invq[mq][r] = 1.f / __shfl(psum[mq], quad * 4 + r, 64);

#pragma unroll
    for (int mq = 0; mq < 2; ++mq)
#pragma unroll
      for (int r = 0; r < 4; ++r) {
        const int qg = qw0 + mq * 16 + quad * 4 + r;
#pragma unroll
        for (int td = 0; td < 4; ++td)
          Ab[hoff + (size_t)qg * PE + td * 16 + ln] =
              f2bf(o[mq][td][r] * invq[mq][r]);
      }
  }
}

// ---------------------------------------------------------------------------
extern "C" void kernel_launch(void* const* d_in, const int* in_sizes, int n_in,
                              void* d_out, int out_size, void* d_ws, size_t ws_size,
                              hipStream_t stream) {
  (void)in_sizes; (void)n_in; (void)out_size; (void)ws_size;
  const float* x  = (const float*)d_in[0];
  const float* Wk = (const float*)d_in[1];
  const float* Wq = (const float*)d_in[2];
  // d_in[3] = Wv : dead in the reference (V = Q bug) — never touched.
  const float* Wo = (const float*)d_in[4];
  const float* bo = (const float*)d_in[5];
  float* out = (float*)d_out;

  char* ws = (char*)d_ws;
  unsigned short* xb  = (unsigned short*)(ws);                       // 16 MiB
  unsigned short* wkb = (unsigned short*)(ws + (16u << 20));         //  2 MiB
  unsigned short* wqb = (unsigned short*)(ws + (18u << 20));         //  2 MiB
  unsigned short* wob = (unsigned short*)(ws + (20u << 20));         //  2 MiB
  unsigned short* QT  = (unsigned short*)(ws + (22u << 20));         // 16 MiB
  unsigned short* Kb  = (unsigned short*)(ws + (38u << 20));         // 16 MiB
  unsigned short* Ab  = xb;  // alias: xb dead after gemm_qk

  const int M = PB * PS;  // 8192

  // 1) fp32 -> bf16
  cvt_kernel<<<dim3(CVT_BLOCKS), dim3(256), 0, stream>>>(
      x, Wk, Wq, Wo, xb, wkb, wqb, wob);

  // 2) fused: Q = x Wq^T (-> QT transposed), K = x Wk^T (-> row-major)
  gemm_qk<<<dim3(PE / 128, M / 128), dim3(256), 0, stream>>>(
      xb, wqb, wkb, QT, Kb);

  // 3) causal attention (V = Q), scale 1/32 — balanced q-tile pairs
  attn_kernel<<<dim3(8, PH, PB), dim3(256), 0, stream>>>(QT, Kb, Ab);

  // 4) out = attn Wo^T + bo (fp32)
  gemm_out<<<dim3(PE / 128, M / 128), dim3(256), 0, stream>>>(
      Ab, wob, bo, out);
}